// Round 1
// 78.440 us; speedup vs baseline: 1.1502x; 1.1502x over previous
//
#include <hip/hip_runtime.h>
#include <math.h>

// Problem constants (reference: N=16, T=2048, D=2)
#define TT     2048
#define LOG2E  1.4426950408889634f
#define LN2    0.6931471805599453f
#define LOG2PI 1.8378770664093453f

// ---------------------------------------------------------------------------
// Kernel 1: pack + prefix scan. One block per n (256 threads, 8 elems/thread).
//   packed[j] = { x_j, y_j, z_j, A_j }
//     bt_j = t_j * LOG2E / softplus(coeff)
//     z_j  = c1*r_j + bt_j            (r_j = x_j^2 + y_j^2, c1 in log2 domain)
//     B_i  = sum_{j<i} exp2(bt_j)     (exclusive prefix, block scan)
//     A_i  = LN2*(c1*r_i - log2(B_i)) + c0   (full per-row epilogue constant)
// ---------------------------------------------------------------------------
__global__ __launch_bounds__(256) void gmsm_scan(
    const float* __restrict__ time,     // N*T
    const float* __restrict__ loc,      // N*T*2
    const float* __restrict__ coeffp,
    const float* __restrict__ lsp,
    float4* __restrict__ packed)
{
    const int n    = blockIdx.x;
    const int tid  = threadIdx.x;
    const int lane = tid & 63;
    const int wv   = tid >> 6;

    const float sp = log1pf(expf(*coeffp));          // softplus(coeff)
    const float ss = LOG2E / sp;
    const float ls = *lsp;
    const float c1 = -0.5f * expf(-2.0f * ls) * LOG2E;
    const float c0 = -(2.0f * ls + LOG2PI);

    const float4* tp = (const float4*)(time + (size_t)n * TT);      // 4 t / vec
    const float4* lp = (const float4*)(loc  + (size_t)n * TT * 2);  // 2 pts / vec
    float4* pk = packed + (size_t)n * TT;

    // 8 consecutive elements per thread
    const float4 t0 = tp[tid * 2 + 0];
    const float4 t1 = tp[tid * 2 + 1];
    const float4 l0 = lp[tid * 4 + 0];
    const float4 l1 = lp[tid * 4 + 1];
    const float4 l2 = lp[tid * 4 + 2];
    const float4 l3 = lp[tid * 4 + 3];

    const float tt[8] = {t0.x, t0.y, t0.z, t0.w, t1.x, t1.y, t1.z, t1.w};
    const float xx[8] = {l0.x, l0.z, l1.x, l1.z, l2.x, l2.z, l3.x, l3.z};
    const float yy[8] = {l0.y, l0.w, l1.y, l1.w, l2.y, l2.w, l3.y, l3.w};

    float bt[8], P[8];
    float run = 0.0f;
    #pragma unroll
    for (int k = 0; k < 8; ++k) {
        bt[k] = tt[k] * ss;
        run += __builtin_amdgcn_exp2f(bt[k]);
        P[k] = run;                                   // inclusive within thread
    }
    const float tot = run;

    // wave inclusive scan of thread totals
    float v = tot;
    #pragma unroll
    for (int d = 1; d < 64; d <<= 1) {
        const float o = __shfl_up(v, d, 64);
        if (lane >= d) v += o;
    }
    __shared__ float wsum[4];
    if (lane == 63) wsum[wv] = v;
    __syncthreads();
    float excl = v - tot;                             // exclusive within wave
    for (int k = 0; k < wv; ++k) excl += wsum[k];     // + previous waves

    #pragma unroll
    for (int k = 0; k < 8; ++k) {
        const int idx = tid * 8 + k;
        const float B = excl + (k ? P[k - 1] : 0.0f); // exclusive prefix at idx
        const float r = fmaf(xx[k], xx[k], yy[k] * yy[k]);
        const float z = fmaf(r, c1, bt[k]);
        const float A = (idx == 0) ? 0.0f
            : fmaf(fmaf(r, c1, -__builtin_amdgcn_logf(B)), LN2, c0);
        pk[idx] = make_float4(xx[k], yy[k], z, A);
    }
}

// ---------------------------------------------------------------------------
// Kernel 2: row-per-lane. Each block owns 64 consecutive rows (lane = row);
// 8 waves split the uniform j-stream round-robin by 64-wide chunks, so every
// packed[j] access is wave-uniform -> s_load / broadcast (no per-lane vL1
// streaming). Inner body: 2 fma + exp2 + add.
//   out_i = LN2*log2( sum_{j<i} exp2(z_j + u_i x_j + v_i y_j) ) + A_i
// ---------------------------------------------------------------------------
__global__ __launch_bounds__(512) void gmsm_main(
    const float4* __restrict__ packed,
    const float* __restrict__ mu0p,
    const float* __restrict__ logstd0p,
    const float* __restrict__ lsp,
    float* __restrict__ out,
    int nrowblk)                                      // N * (TT/64)
{
    // complement swizzle: pair heavy (high base) with light (low base) blocks
    const int b    = blockIdx.x;
    const int half = nrowblk >> 1;
    const int g    = (b < half) ? (b << 1) : ((((nrowblk - 1) - b) << 1) | 1);
    const int n    = g >> 5;                          // / (TT/64)
    const int base = (g & 31) << 6;

    const int tid  = threadIdx.x;
    const int lane = tid & 63;
    const int w    = __builtin_amdgcn_readfirstlane(tid >> 6);

    const float4* __restrict__ pk = packed + (size_t)n * TT;

    const float ls   = *lsp;
    const float m2c1 = expf(-2.0f * ls) * LOG2E;      // = -2*c1 > 0
    const float4 pi  = pk[base + lane];               // this lane's row
    const float u    = m2c1 * pi.x;
    const float v    = m2c1 * pi.y;

    float s = 0.0f;
    const int cfull = base >> 6;                      // # full 64-wide chunks

    for (int c = w; c < cfull; c += 8) {
        const float4* cp = pk + (c << 6);
        #pragma unroll 8
        for (int jj = 0; jj < 64; ++jj) {
            const float4 f = cp[jj];                  // wave-uniform address
            s += __builtin_amdgcn_exp2f(fmaf(u, f.x, fmaf(v, f.y, f.z)));
        }
    }
    // triangular tail chunk: j = base + jj, active iff jj < lane
    if (w == (cfull & 7)) {
        const float4* cp = pk + base;
        for (int jj = 0; jj < 63; ++jj) {
            const float4 f = cp[jj];
            const float e = __builtin_amdgcn_exp2f(fmaf(u, f.x, fmaf(v, f.y, f.z)));
            s += (jj < lane) ? e : 0.0f;
        }
    }

    __shared__ float lds[8 * 64];
    lds[tid] = s;
    __syncthreads();

    if (tid < 64) {
        float stot = 0.0f;
        #pragma unroll
        for (int k = 0; k < 8; ++k) stot += lds[(k << 6) | tid];
        const int i = base + tid;
        float res;
        if (i == 0) {
            const float mu0 = *mu0p, l0 = *logstd0p;
            const float inv = expf(-l0);
            const float4 p0 = pk[0];
            const float tx = (p0.x - mu0) * inv;
            const float ty = (p0.y - mu0) * inv;
            res = -0.5f * (tx * tx + ty * ty + 4.0f * l0 + 2.0f * LOG2PI);
        } else {
            const float A = pk[i].w;
            res = fmaf(__builtin_amdgcn_logf(stot), LN2, A);
        }
        out[(size_t)n * TT + i] = res;
    }
}

extern "C" void kernel_launch(void* const* d_in, const int* in_sizes, int n_in,
                              void* d_out, int out_size, void* d_ws, size_t ws_size,
                              hipStream_t stream) {
    const float* time   = (const float*)d_in[0];
    const float* loc    = (const float*)d_in[1];
    const float* mu0    = (const float*)d_in[2];
    const float* logstd = (const float*)d_in[3];
    const float* coeff  = (const float*)d_in[4];
    const float* sls    = (const float*)d_in[5];
    float* out = (float*)d_out;

    const int nrows = out_size;                 // N * T = 32768
    const int N     = nrows / TT;               // 16
    const int nrowblk = nrows >> 6;             // 512
    float4* packed = (float4*)d_ws;             // N*T*16 B = 512 KB scratch

    gmsm_scan<<<N, 256, 0, stream>>>(time, loc, coeff, sls, packed);
    gmsm_main<<<nrowblk, 512, 0, stream>>>(packed, mu0, logstd, sls, out, nrowblk);
}